// Round 1
// baseline (321381.128 us; speedup 1.0000x reference)
//
#include <hip/hip_runtime.h>
#include <cstdint>
#include <cstddef>

typedef _Float16 h2v __attribute__((ext_vector_type(2)));
typedef _Float16 h8v __attribute__((ext_vector_type(8)));

#define NEG_SLOPE 0.2f
#define BN_EPS 1e-5f
#define BM 64
#define BN 64
#define BK 16

__device__ __forceinline__ float lrelu(float x) { return x > 0.f ? x : NEG_SLOPE * x; }

__device__ __forceinline__ unsigned fenc(float f) {
  unsigned b = __float_as_uint(f);
  return (b & 0x80000000u) ? ~b : (b | 0x80000000u);
}
__device__ __forceinline__ float fdec(unsigned u) {
  return (u & 0x80000000u) ? __uint_as_float(u & 0x7fffffffu) : __uint_as_float(~u);
}

__device__ __forceinline__ float fdot2f(h2v a, h2v b, float c) {
#if __has_builtin(__builtin_amdgcn_fdot2)
  return __builtin_amdgcn_fdot2(a, b, c, false);
#else
  return c + (float)a.x * (float)b.x + (float)a.y * (float)b.y;
#endif
}
__device__ __forceinline__ float sigf(float x) { return 1.f / (1.f + __expf(-x)); }
__device__ __forceinline__ float tanhfast(float x) {
  x = fminf(fmaxf(x, -20.f), 20.f);
  float e = __expf(2.f * x);
  return (e - 1.f) / (e + 1.f);
}

// ---------------- GAT layer 1 (rank-1 collapse) ----------------

__global__ __launch_bounds__(256) void k_prep_c(const float* __restrict__ W1,
                                                const float* __restrict__ as1,
                                                const float* __restrict__ ad1,
                                                float* __restrict__ c12) {
  __shared__ float r1[256], r2[256];
  int j = threadIdx.x;
  float wv = W1[j];
  r1[j] = wv * as1[j];
  r2[j] = wv * ad1[j];
  __syncthreads();
  for (int s = 128; s > 0; s >>= 1) {
    if (j < s) { r1[j] += r1[j + s]; r2[j] += r2[j + s]; }
    __syncthreads();
  }
  if (j == 0) { c12[0] = r1[0]; c12[1] = r2[0]; }
}

__global__ __launch_bounds__(256) void k_a1(const float* __restrict__ x, const float* __restrict__ c12,
                                            float* __restrict__ a1s, float* __restrict__ a1d, int N) {
  int i = blockIdx.x * 256 + threadIdx.x;
  if (i < N) {
    float xv = x[i];
    a1s[i] = c12[0] * xv;
    a1d[i] = c12[1] * xv;
  }
}

__global__ __launch_bounds__(256) void k_edge_max(const float* __restrict__ as_, const float* __restrict__ ad_,
                                                  unsigned* __restrict__ menc, const int* __restrict__ src,
                                                  const int* __restrict__ dst, int E, int N) {
  int i = blockIdx.x * 256 + threadIdx.x;
  if (i >= E + N) return;
  int s, d;
  if (i < E) { s = src[i]; d = dst[i]; } else { s = i - E; d = s; }
  float e = lrelu(as_[s] + ad_[d]);
  atomicMax(&menc[d], fenc(e));
}

__global__ __launch_bounds__(256) void k_gat1_edge_sum(const float* __restrict__ as_, const float* __restrict__ ad_,
                                                       const unsigned* __restrict__ menc, const int* __restrict__ src,
                                                       const int* __restrict__ dst, const float* __restrict__ x,
                                                       float* __restrict__ z, float* __restrict__ uacc, int E, int N) {
  int i = blockIdx.x * 256 + threadIdx.x;
  if (i >= E + N) return;
  int s, d;
  if (i < E) { s = src[i]; d = dst[i]; } else { s = i - E; d = s; }
  float e = lrelu(as_[s] + ad_[d]);
  float p = __expf(e - fdec(menc[d]));
  atomicAdd(&z[d], p);
  atomicAdd(&uacc[d], p * x[s]);
}

__global__ __launch_bounds__(256) void k_gat1_node(const float* __restrict__ uacc, const float* __restrict__ z1,
                                                   const float* __restrict__ W1, const float* __restrict__ b1,
                                                   const float* __restrict__ gamma, const float* __restrict__ beta,
                                                   const float* __restrict__ mean, const float* __restrict__ var,
                                                   float* __restrict__ h1) {
  int n = blockIdx.x, j = threadIdx.x;
  float u = uacc[n] / z1[n];
  float v = u * W1[j] + b1[j];
  v = (v - mean[j]) * rsqrtf(var[j] + BN_EPS) * gamma[j] + beta[j];
  h1[(size_t)n * 256 + j] = fmaxf(v, 0.f);
}

// ---------------- generic fp32 tiled GEMM: C[M,N] = A[M,K] * B[K,N] ----------------

__global__ __launch_bounds__(256) void k_gemm_f32(const float* __restrict__ A, const float* __restrict__ B,
                                                  float* __restrict__ C, int M, int N, int K) {
  __shared__ float As[BK][BM];
  __shared__ float Bs[BK][BN];
  int tid = threadIdx.x;
  int m0 = blockIdx.x * BM, n0 = blockIdx.y * BN;
  int lm = tid >> 2;
  int lk4 = (tid & 3) * 4;
  int bn_ = tid & 63;
  int bkq = (tid >> 6) * 4;
  int tm = (tid >> 4) * 4, tn = (tid & 15) * 4;
  float acc[4][4] = {};
  for (int k0 = 0; k0 < K; k0 += BK) {
    float4 av4 = make_float4(0.f, 0.f, 0.f, 0.f);
    if (m0 + lm < M) av4 = *(const float4*)(A + (size_t)(m0 + lm) * K + k0 + lk4);
    As[lk4 + 0][lm] = av4.x;
    As[lk4 + 1][lm] = av4.y;
    As[lk4 + 2][lm] = av4.z;
    As[lk4 + 3][lm] = av4.w;
#pragma unroll
    for (int c = 0; c < 4; ++c) {
      int k = k0 + bkq + c;
      Bs[bkq + c][bn_] = (k < K) ? B[(size_t)k * N + n0 + bn_] : 0.f;
    }
    __syncthreads();
#pragma unroll
    for (int kk = 0; kk < BK; ++kk) {
      float av[4], bv[4];
#pragma unroll
      for (int i = 0; i < 4; ++i) { av[i] = As[kk][tm + i]; bv[i] = Bs[kk][tn + i]; }
#pragma unroll
      for (int i = 0; i < 4; ++i)
#pragma unroll
        for (int jj = 0; jj < 4; ++jj) acc[i][jj] = fmaf(av[i], bv[jj], acc[i][jj]);
    }
    __syncthreads();
  }
#pragma unroll
  for (int i = 0; i < 4; ++i) {
    int m = m0 + tm + i;
    if (m < M) {
      float4 v = make_float4(acc[i][0], acc[i][1], acc[i][2], acc[i][3]);
      *(float4*)(C + (size_t)m * N + n0 + tn) = v;
    }
  }
}

// ---------------- row dots for GAT2 attention scalars ----------------

__global__ __launch_bounds__(256) void k_rowdots(const float* __restrict__ xw2, const float* __restrict__ as2,
                                                 const float* __restrict__ ad2, float* __restrict__ a2s,
                                                 float* __restrict__ a2d) {
  __shared__ float r1[256], r2[256];
  int n = blockIdx.x, j = threadIdx.x;
  float v = xw2[(size_t)n * 256 + j];
  r1[j] = v * as2[j];
  r2[j] = v * ad2[j];
  __syncthreads();
  for (int s = 128; s > 0; s >>= 1) {
    if (j < s) { r1[j] += r1[j + s]; r2[j] += r2[j + s]; }
    __syncthreads();
  }
  if (j == 0) { a2s[n] = r1[0]; a2d[n] = r2[0]; }
}

__global__ __launch_bounds__(256) void k_gat2_scatter(const float* __restrict__ a2s, const float* __restrict__ a2d,
                                                      const unsigned* __restrict__ m2, const int* __restrict__ src,
                                                      const int* __restrict__ dst, const float* __restrict__ xw2,
                                                      float* __restrict__ z2, float* __restrict__ acc2, int E, int N) {
  int j = threadIdx.x;
  for (int i = blockIdx.x; i < E + N; i += gridDim.x) {
    int s, d;
    if (i < E) { s = src[i]; d = dst[i]; } else { s = i - E; d = s; }
    float e = lrelu(a2s[s] + a2d[d]);
    float p = __expf(e - fdec(m2[d]));
    if (j == 0) atomicAdd(&z2[d], p);
    atomicAdd(&acc2[(size_t)d * 256 + j], p * xw2[(size_t)s * 256 + j]);
  }
}

__global__ __launch_bounds__(256) void k_gat2_node(float* __restrict__ acc2, const float* __restrict__ z2,
                                                   const float* __restrict__ b2, const float* __restrict__ gamma,
                                                   const float* __restrict__ beta, const float* __restrict__ mean,
                                                   const float* __restrict__ var) {
  int n = blockIdx.x, j = threadIdx.x;
  size_t idx = (size_t)n * 256 + j;
  float v = acc2[idx] / z2[n] + b2[j];
  v = (v - mean[j]) * rsqrtf(var[j] + BN_EPS) * gamma[j] + beta[j];
  acc2[idx] = fmaxf(v, 0.f);
}

// ---------------- gi GEMM: out[M,Nout](f16) = A[M,K] * W[Nout,K]^T + bias ----------------
// mode 0: A = gathered edge features [h2[src], h2[dst], ea]  (K=515)
// mode 1: A = f16 transposed [K, M] (g0 stored feature-major)  (K=256)

__global__ __launch_bounds__(256) void k_gemm_gi(const _Float16* __restrict__ Af16, const float* __restrict__ h2,
                                                 const int* __restrict__ src, const int* __restrict__ dst,
                                                 const float* __restrict__ ea, const float* __restrict__ W,
                                                 const float* __restrict__ bias, _Float16* __restrict__ out,
                                                 int M, int Nout, int K, int mode) {
  __shared__ float As[BK][BM];
  __shared__ float Bs[BK][BN];
  int tid = threadIdx.x;
  int m0 = blockIdx.x * BM, n0 = blockIdx.y * BN;
  int lm = tid >> 2;
  int lk4 = (tid & 3) * 4;
  int bn_ = tid >> 2;       // 0..63 (output col for B load)
  int bk4 = (tid & 3) * 4;  // 0,4,8,12
  int tm = (tid >> 4) * 4, tn = (tid & 15) * 4;
  float acc[4][4] = {};
  int s_m = 0, d_m = 0;
  if (mode == 0) { s_m = src[m0 + lm]; d_m = dst[m0 + lm]; }
  for (int k0 = 0; k0 < K; k0 += BK) {
#pragma unroll
    for (int c = 0; c < 4; ++c) {
      int k = k0 + lk4 + c;
      float v = 0.f;
      if (k < K) {
        if (mode == 0) {
          if (k < 256) v = h2[(size_t)s_m * 256 + k];
          else if (k < 512) v = h2[(size_t)d_m * 256 + (k - 256)];
          else v = ea[(size_t)(m0 + lm) * 3 + (k - 512)];
        } else {
          v = (float)Af16[(size_t)k * M + (m0 + lm)];
        }
      }
      As[lk4 + c][lm] = v;
    }
#pragma unroll
    for (int c = 0; c < 4; ++c) {
      int k = k0 + bk4 + c;
      Bs[bk4 + c][bn_] = (k < K) ? W[(size_t)(n0 + bn_) * K + k] : 0.f;
    }
    __syncthreads();
#pragma unroll
    for (int kk = 0; kk < BK; ++kk) {
      float av[4], bv[4];
#pragma unroll
      for (int i = 0; i < 4; ++i) { av[i] = As[kk][tm + i]; bv[i] = Bs[kk][tn + i]; }
#pragma unroll
      for (int i = 0; i < 4; ++i)
#pragma unroll
        for (int jj = 0; jj < 4; ++jj) acc[i][jj] = fmaf(av[i], bv[jj], acc[i][jj]);
    }
    __syncthreads();
  }
#pragma unroll
  for (int i = 0; i < 4; ++i)
#pragma unroll
    for (int jj = 0; jj < 4; ++jj)
      out[(size_t)(m0 + tm + i) * Nout + (n0 + tn + jj)] = (_Float16)(acc[i][jj] + bias[n0 + tn + jj]);
}

// ---------------- sequential GRU scan, single workgroup ----------------
// 256 threads; thread j owns hidden unit j and holds Whh rows j (r), j+256 (z),
// j+512 (n) as f16 pairs in registers (384 VGPRs). h broadcast via LDS (f16,
// double buffered), one barrier per step. Output written feature-major
// gout[j*T + t] with 8-step register batching (16B stores).

__global__ __launch_bounds__(256, 1) void k_gru_scan(const float* __restrict__ Whh, const float* __restrict__ bhh,
                                                     const _Float16* __restrict__ gi, _Float16* __restrict__ gout,
                                                     int T) {
  int j = threadIdx.x;
  h2v wr[128], wz[128], wn[128];
  {
    const float2* r0 = (const float2*)(Whh + (size_t)j * 256);
    const float2* r1 = (const float2*)(Whh + (size_t)(j + 256) * 256);
    const float2* r2 = (const float2*)(Whh + (size_t)(j + 512) * 256);
#pragma unroll
    for (int k = 0; k < 128; ++k) {
      float2 a = r0[k]; h2v va; va.x = (_Float16)a.x; va.y = (_Float16)a.y; wr[k] = va;
      float2 b = r1[k]; h2v vb; vb.x = (_Float16)b.x; vb.y = (_Float16)b.y; wz[k] = vb;
      float2 c = r2[k]; h2v vc; vc.x = (_Float16)c.x; vc.y = (_Float16)c.y; wn[k] = vc;
    }
  }
  float bhr = bhh[j], bhz = bhh[j + 256], bhn = bhh[j + 512];
  __shared__ _Float16 hb[2][256];
  hb[0][j] = (_Float16)0.f;
  hb[1][j] = (_Float16)0.f;
  __syncthreads();
  float h = 0.f;
  float pr = (float)gi[j], pz = (float)gi[256 + j], pn = (float)gi[512 + j];
  for (int t0 = 0; t0 < T; t0 += 8) {
    h8v sb;
#pragma unroll
    for (int u = 0; u < 8; ++u) {
      int t = t0 + u;
      float gir = pr, giz = pz, gin = pn;
      if (t + 1 < T) {
        const _Float16* gp = gi + (size_t)(t + 1) * 768;
        pr = (float)gp[j];
        pz = (float)gp[256 + j];
        pn = (float)gp[512 + j];
      }
      const h2v* hp = (const h2v*)hb[u & 1];
      float ar = bhr, az = bhz, an = bhn;
#pragma unroll
      for (int k = 0; k < 128; ++k) {
        h2v hk = hp[k];
        ar = fdot2f(wr[k], hk, ar);
        az = fdot2f(wz[k], hk, az);
        an = fdot2f(wn[k], hk, an);
      }
      float r = sigf(gir + ar);
      float zt = sigf(giz + az);
      float nn = tanhfast(gin + r * an);
      h = (1.f - zt) * nn + zt * h;
      sb[u] = (_Float16)h;
      hb[(u & 1) ^ 1][j] = (_Float16)h;
      __syncthreads();
    }
    *(h8v*)(gout + (size_t)j * T + t0) = sb;
  }
}

// ---------------- final MLP: out[t] = Wlin2 . relu(Wlin1 . g1_t + blin1) + blin2 ----------------

__global__ __launch_bounds__(128) void k_final(const _Float16* __restrict__ g1T, const float* __restrict__ Wlin1,
                                               const float* __restrict__ blin1, const float* __restrict__ Wlin2,
                                               const float* __restrict__ blin2, float* __restrict__ out, int E) {
  int j = threadIdx.x;  // 0..127
  float w[256];
#pragma unroll
  for (int k = 0; k < 256; ++k) w[k] = Wlin1[(size_t)j * 256 + k];
  float bj = blin1[j], w2j = Wlin2[j], b2v = blin2[0];
  __shared__ float gsf[256];
  __shared__ float red[128];
  for (int t = blockIdx.x; t < E; t += gridDim.x) {
    gsf[j] = (float)g1T[(size_t)j * E + t];
    gsf[j + 128] = (float)g1T[(size_t)(j + 128) * E + t];
    __syncthreads();
    float acc = 0.f;
#pragma unroll
    for (int k = 0; k < 256; ++k) acc = fmaf(w[k], gsf[k], acc);
    float v = fmaxf(acc + bj, 0.f) * w2j;
    red[j] = v;
    __syncthreads();
    for (int s = 64; s > 0; s >>= 1) {
      if (j < s) red[j] += red[j + s];
      __syncthreads();
    }
    if (j == 0) out[t] = red[0] + b2v;
    __syncthreads();
  }
}

// ---------------- launch ----------------

extern "C" void kernel_launch(void* const* d_in, const int* in_sizes, int n_in,
                              void* d_out, int out_size, void* d_ws, size_t ws_size,
                              hipStream_t stream) {
  (void)n_in; (void)out_size; (void)ws_size;
  const float* x = (const float*)d_in[0];
  const int* ei = (const int*)d_in[1];
  const float* ea = (const float*)d_in[2];
  const float* W1 = (const float*)d_in[3];
  const float* as1 = (const float*)d_in[4];
  const float* ad1 = (const float*)d_in[5];
  const float* b1 = (const float*)d_in[6];
  const float* gamma1 = (const float*)d_in[7];
  const float* beta1 = (const float*)d_in[8];
  const float* mean1 = (const float*)d_in[9];
  const float* var1 = (const float*)d_in[10];
  const float* W2 = (const float*)d_in[11];
  const float* as2 = (const float*)d_in[12];
  const float* ad2 = (const float*)d_in[13];
  const float* b2 = (const float*)d_in[14];
  const float* gamma2 = (const float*)d_in[15];
  const float* beta2 = (const float*)d_in[16];
  const float* mean2 = (const float*)d_in[17];
  const float* var2 = (const float*)d_in[18];
  const float* Wih0 = (const float*)d_in[19];
  const float* Whh0 = (const float*)d_in[20];
  const float* bih0 = (const float*)d_in[21];
  const float* bhh0 = (const float*)d_in[22];
  const float* Wih1 = (const float*)d_in[23];
  const float* Whh1 = (const float*)d_in[24];
  const float* bih1 = (const float*)d_in[25];
  const float* bhh1 = (const float*)d_in[26];
  const float* Wlin1 = (const float*)d_in[27];
  const float* blin1 = (const float*)d_in[28];
  const float* Wlin2 = (const float*)d_in[29];
  const float* blin2 = (const float*)d_in[30];

  int N = in_sizes[0];
  int E = in_sizes[1] / 2;
  const int* src = ei;
  const int* dst = ei + E;

  char* wsp = (char*)d_ws;
  size_t off = 0;
  auto carve = [&](size_t bytes) -> void* {
    void* p = wsp + off;
    off = (off + bytes + 255) & ~(size_t)255;
    return p;
  };
  float* c12 = (float*)carve(2 * sizeof(float));
  float* a1s = (float*)carve((size_t)N * 4);
  float* a1d = (float*)carve((size_t)N * 4);
  unsigned* m1 = (unsigned*)carve((size_t)N * 4);
  float* z1 = (float*)carve((size_t)N * 4);
  float* uacc = (float*)carve((size_t)N * 4);
  float* h1 = (float*)carve((size_t)N * 256 * 4);
  float* xw2 = (float*)carve((size_t)N * 256 * 4);
  float* a2s = (float*)carve((size_t)N * 4);
  float* a2d = (float*)carve((size_t)N * 4);
  unsigned* m2 = (unsigned*)carve((size_t)N * 4);
  float* z2 = (float*)carve((size_t)N * 4);
  float* acc2 = (float*)carve((size_t)N * 256 * 4);          // becomes h2 in-place
  _Float16* gi = (_Float16*)carve((size_t)E * 768 * 2);      // reused for gi0 then gi1
  _Float16* g0 = (_Float16*)carve((size_t)E * 256 * 2);      // feature-major [256, E]
  _Float16* g1 = (_Float16*)carve((size_t)E * 256 * 2);      // feature-major [256, E]

  hipMemsetAsync(m1, 0, (size_t)N * 4, stream);
  hipMemsetAsync(z1, 0, (size_t)N * 4, stream);
  hipMemsetAsync(uacc, 0, (size_t)N * 4, stream);
  hipMemsetAsync(m2, 0, (size_t)N * 4, stream);
  hipMemsetAsync(z2, 0, (size_t)N * 4, stream);
  hipMemsetAsync(acc2, 0, (size_t)N * 256 * 4, stream);

  int eb = (E + N + 255) / 256;

  k_prep_c<<<1, 256, 0, stream>>>(W1, as1, ad1, c12);
  k_a1<<<(N + 255) / 256, 256, 0, stream>>>(x, c12, a1s, a1d, N);
  k_edge_max<<<eb, 256, 0, stream>>>(a1s, a1d, m1, src, dst, E, N);
  k_gat1_edge_sum<<<eb, 256, 0, stream>>>(a1s, a1d, m1, src, dst, x, z1, uacc, E, N);
  k_gat1_node<<<N, 256, 0, stream>>>(uacc, z1, W1, b1, gamma1, beta1, mean1, var1, h1);

  dim3 gx((N + BM - 1) / BM, 256 / BN);
  k_gemm_f32<<<gx, 256, 0, stream>>>(h1, W2, xw2, N, 256, 256);
  k_rowdots<<<N, 256, 0, stream>>>(xw2, as2, ad2, a2s, a2d);
  k_edge_max<<<eb, 256, 0, stream>>>(a2s, a2d, m2, src, dst, E, N);
  k_gat2_scatter<<<4096, 256, 0, stream>>>(a2s, a2d, m2, src, dst, xw2, z2, acc2, E, N);
  k_gat2_node<<<N, 256, 0, stream>>>(acc2, z2, b2, gamma2, beta2, mean2, var2);

  dim3 gg(E / BM, 768 / BN);
  k_gemm_gi<<<gg, 256, 0, stream>>>(nullptr, acc2, src, dst, ea, Wih0, bih0, gi, E, 768, 515, 0);
  k_gru_scan<<<1, 256, 0, stream>>>(Whh0, bhh0, gi, g0, E);
  k_gemm_gi<<<gg, 256, 0, stream>>>(g0, nullptr, src, dst, ea, Wih1, bih1, gi, E, 768, 256, 1);
  k_gru_scan<<<1, 256, 0, stream>>>(Whh1, bhh1, gi, g1, E);

  k_final<<<1024, 128, 0, stream>>>(g1, Wlin1, blin1, Wlin2, blin2, (float*)d_out, E);
}

// Round 3
// 154573.145 us; speedup vs baseline: 2.0792x; 2.0792x over previous
//
#include <hip/hip_runtime.h>
#include <cstdint>
#include <cstddef>

typedef _Float16 h2v __attribute__((ext_vector_type(2)));
typedef _Float16 h8v __attribute__((ext_vector_type(8)));

#define NEG_SLOPE 0.2f
#define BN_EPS 1e-5f
#define BM 64
#define BN 64
#define BK 16

__device__ __forceinline__ float lrelu(float x) { return x > 0.f ? x : NEG_SLOPE * x; }

__device__ __forceinline__ unsigned fenc(float f) {
  unsigned b = __float_as_uint(f);
  return (b & 0x80000000u) ? ~b : (b | 0x80000000u);
}
__device__ __forceinline__ float fdec(unsigned u) {
  return (u & 0x80000000u) ? __uint_as_float(u & 0x7fffffffu) : __uint_as_float(~u);
}

__device__ __forceinline__ float fdot2f(h2v a, h2v b, float c) {
#if __has_builtin(__builtin_amdgcn_fdot2)
  return __builtin_amdgcn_fdot2(a, b, c, false);
#else
  return c + (float)a.x * (float)b.x + (float)a.y * (float)b.y;
#endif
}
__device__ __forceinline__ float sigf(float x) { return 1.f / (1.f + __expf(-x)); }
__device__ __forceinline__ float tanhfast(float x) {
  x = fminf(fmaxf(x, -20.f), 20.f);
  float e = __expf(2.f * x);
  return (e - 1.f) / (e + 1.f);
}

// ---------------- GAT layer 1 (rank-1 collapse) ----------------

__global__ __launch_bounds__(256) void k_prep_c(const float* __restrict__ W1,
                                                const float* __restrict__ as1,
                                                const float* __restrict__ ad1,
                                                float* __restrict__ c12) {
  __shared__ float r1[256], r2[256];
  int j = threadIdx.x;
  float wv = W1[j];
  r1[j] = wv * as1[j];
  r2[j] = wv * ad1[j];
  __syncthreads();
  for (int s = 128; s > 0; s >>= 1) {
    if (j < s) { r1[j] += r1[j + s]; r2[j] += r2[j + s]; }
    __syncthreads();
  }
  if (j == 0) { c12[0] = r1[0]; c12[1] = r2[0]; }
}

__global__ __launch_bounds__(256) void k_a1(const float* __restrict__ x, const float* __restrict__ c12,
                                            float* __restrict__ a1s, float* __restrict__ a1d, int N) {
  int i = blockIdx.x * 256 + threadIdx.x;
  if (i < N) {
    float xv = x[i];
    a1s[i] = c12[0] * xv;
    a1d[i] = c12[1] * xv;
  }
}

__global__ __launch_bounds__(256) void k_edge_max(const float* __restrict__ as_, const float* __restrict__ ad_,
                                                  unsigned* __restrict__ menc, const int* __restrict__ src,
                                                  const int* __restrict__ dst, int E, int N) {
  int i = blockIdx.x * 256 + threadIdx.x;
  if (i >= E + N) return;
  int s, d;
  if (i < E) { s = src[i]; d = dst[i]; } else { s = i - E; d = s; }
  float e = lrelu(as_[s] + ad_[d]);
  atomicMax(&menc[d], fenc(e));
}

__global__ __launch_bounds__(256) void k_gat1_edge_sum(const float* __restrict__ as_, const float* __restrict__ ad_,
                                                       const unsigned* __restrict__ menc, const int* __restrict__ src,
                                                       const int* __restrict__ dst, const float* __restrict__ x,
                                                       float* __restrict__ z, float* __restrict__ uacc, int E, int N) {
  int i = blockIdx.x * 256 + threadIdx.x;
  if (i >= E + N) return;
  int s, d;
  if (i < E) { s = src[i]; d = dst[i]; } else { s = i - E; d = s; }
  float e = lrelu(as_[s] + ad_[d]);
  float p = __expf(e - fdec(menc[d]));
  atomicAdd(&z[d], p);
  atomicAdd(&uacc[d], p * x[s]);
}

__global__ __launch_bounds__(256) void k_gat1_node(const float* __restrict__ uacc, const float* __restrict__ z1,
                                                   const float* __restrict__ W1, const float* __restrict__ b1,
                                                   const float* __restrict__ gamma, const float* __restrict__ beta,
                                                   const float* __restrict__ mean, const float* __restrict__ var,
                                                   float* __restrict__ h1) {
  int n = blockIdx.x, j = threadIdx.x;
  float u = uacc[n] / z1[n];
  float v = u * W1[j] + b1[j];
  v = (v - mean[j]) * rsqrtf(var[j] + BN_EPS) * gamma[j] + beta[j];
  h1[(size_t)n * 256 + j] = fmaxf(v, 0.f);
}

// ---------------- generic fp32 tiled GEMM: C[M,N] = A[M,K] * B[K,N] ----------------

__global__ __launch_bounds__(256) void k_gemm_f32(const float* __restrict__ A, const float* __restrict__ B,
                                                  float* __restrict__ C, int M, int N, int K) {
  __shared__ float As[BK][BM];
  __shared__ float Bs[BK][BN];
  int tid = threadIdx.x;
  int m0 = blockIdx.x * BM, n0 = blockIdx.y * BN;
  int lm = tid >> 2;
  int lk4 = (tid & 3) * 4;
  int bn_ = tid & 63;
  int bkq = (tid >> 6) * 4;
  int tm = (tid >> 4) * 4, tn = (tid & 15) * 4;
  float acc[4][4] = {};
  for (int k0 = 0; k0 < K; k0 += BK) {
    float4 av4 = make_float4(0.f, 0.f, 0.f, 0.f);
    if (m0 + lm < M) av4 = *(const float4*)(A + (size_t)(m0 + lm) * K + k0 + lk4);
    As[lk4 + 0][lm] = av4.x;
    As[lk4 + 1][lm] = av4.y;
    As[lk4 + 2][lm] = av4.z;
    As[lk4 + 3][lm] = av4.w;
#pragma unroll
    for (int c = 0; c < 4; ++c) {
      int k = k0 + bkq + c;
      Bs[bkq + c][bn_] = (k < K) ? B[(size_t)k * N + n0 + bn_] : 0.f;
    }
    __syncthreads();
#pragma unroll
    for (int kk = 0; kk < BK; ++kk) {
      float av[4], bv[4];
#pragma unroll
      for (int i = 0; i < 4; ++i) { av[i] = As[kk][tm + i]; bv[i] = Bs[kk][tn + i]; }
#pragma unroll
      for (int i = 0; i < 4; ++i)
#pragma unroll
        for (int jj = 0; jj < 4; ++jj) acc[i][jj] = fmaf(av[i], bv[jj], acc[i][jj]);
    }
    __syncthreads();
  }
#pragma unroll
  for (int i = 0; i < 4; ++i) {
    int m = m0 + tm + i;
    if (m < M) {
      float4 v = make_float4(acc[i][0], acc[i][1], acc[i][2], acc[i][3]);
      *(float4*)(C + (size_t)m * N + n0 + tn) = v;
    }
  }
}

// ---------------- row dots for GAT2 attention scalars ----------------

__global__ __launch_bounds__(256) void k_rowdots(const float* __restrict__ xw2, const float* __restrict__ as2,
                                                 const float* __restrict__ ad2, float* __restrict__ a2s,
                                                 float* __restrict__ a2d) {
  __shared__ float r1[256], r2[256];
  int n = blockIdx.x, j = threadIdx.x;
  float v = xw2[(size_t)n * 256 + j];
  r1[j] = v * as2[j];
  r2[j] = v * ad2[j];
  __syncthreads();
  for (int s = 128; s > 0; s >>= 1) {
    if (j < s) { r1[j] += r1[j + s]; r2[j] += r2[j + s]; }
    __syncthreads();
  }
  if (j == 0) { a2s[n] = r1[0]; a2d[n] = r2[0]; }
}

__global__ __launch_bounds__(256) void k_gat2_scatter(const float* __restrict__ a2s, const float* __restrict__ a2d,
                                                      const unsigned* __restrict__ m2, const int* __restrict__ src,
                                                      const int* __restrict__ dst, const float* __restrict__ xw2,
                                                      float* __restrict__ z2, float* __restrict__ acc2, int E, int N) {
  int j = threadIdx.x;
  for (int i = blockIdx.x; i < E + N; i += gridDim.x) {
    int s, d;
    if (i < E) { s = src[i]; d = dst[i]; } else { s = i - E; d = s; }
    float e = lrelu(a2s[s] + a2d[d]);
    float p = __expf(e - fdec(m2[d]));
    if (j == 0) atomicAdd(&z2[d], p);
    atomicAdd(&acc2[(size_t)d * 256 + j], p * xw2[(size_t)s * 256 + j]);
  }
}

__global__ __launch_bounds__(256) void k_gat2_node(float* __restrict__ acc2, const float* __restrict__ z2,
                                                   const float* __restrict__ b2, const float* __restrict__ gamma,
                                                   const float* __restrict__ beta, const float* __restrict__ mean,
                                                   const float* __restrict__ var) {
  int n = blockIdx.x, j = threadIdx.x;
  size_t idx = (size_t)n * 256 + j;
  float v = acc2[idx] / z2[n] + b2[j];
  v = (v - mean[j]) * rsqrtf(var[j] + BN_EPS) * gamma[j] + beta[j];
  acc2[idx] = fmaxf(v, 0.f);
}

// ---------------- gi GEMM: outT[Nout,M](f16) = (A[M,K] * W[Nout,K]^T + bias)^T ----------------
// Output stored FEATURE-MAJOR: out[n*M + m], so the GRU scan can load each
// gate-row as contiguous h8v blocks across time.
// mode 0: A = gathered edge features [h2[src], h2[dst], ea]  (K=515)
// mode 1: A = f16 feature-major [K, M] (g0 from scan0)        (K=256)

__global__ __launch_bounds__(256) void k_gemm_gi(const _Float16* __restrict__ Af16, const float* __restrict__ h2,
                                                 const int* __restrict__ src, const int* __restrict__ dst,
                                                 const float* __restrict__ ea, const float* __restrict__ W,
                                                 const float* __restrict__ bias, _Float16* __restrict__ out,
                                                 int M, int Nout, int K, int mode) {
  __shared__ float As[BK][BM];
  __shared__ float Bs[BK][BN];
  int tid = threadIdx.x;
  int m0 = blockIdx.x * BM, n0 = blockIdx.y * BN;
  int lm = tid >> 2;
  int lk4 = (tid & 3) * 4;
  int bn_ = tid >> 2;       // 0..63 (output col for B load)
  int bk4 = (tid & 3) * 4;  // 0,4,8,12
  int tm = (tid >> 4) * 4, tn = (tid & 15) * 4;
  float acc[4][4] = {};
  int s_m = 0, d_m = 0;
  if (mode == 0) { s_m = src[m0 + lm]; d_m = dst[m0 + lm]; }
  for (int k0 = 0; k0 < K; k0 += BK) {
#pragma unroll
    for (int c = 0; c < 4; ++c) {
      int k = k0 + lk4 + c;
      float v = 0.f;
      if (k < K) {
        if (mode == 0) {
          if (k < 256) v = h2[(size_t)s_m * 256 + k];
          else if (k < 512) v = h2[(size_t)d_m * 256 + (k - 256)];
          else v = ea[(size_t)(m0 + lm) * 3 + (k - 512)];
        } else {
          v = (float)Af16[(size_t)k * M + (m0 + lm)];
        }
      }
      As[lk4 + c][lm] = v;
    }
#pragma unroll
    for (int c = 0; c < 4; ++c) {
      int k = k0 + bk4 + c;
      Bs[bk4 + c][bn_] = (k < K) ? W[(size_t)(n0 + bn_) * K + k] : 0.f;
    }
    __syncthreads();
#pragma unroll
    for (int kk = 0; kk < BK; ++kk) {
      float av[4], bv[4];
#pragma unroll
      for (int i = 0; i < 4; ++i) { av[i] = As[kk][tm + i]; bv[i] = Bs[kk][tn + i]; }
#pragma unroll
      for (int i = 0; i < 4; ++i)
#pragma unroll
        for (int jj = 0; jj < 4; ++jj) acc[i][jj] = fmaf(av[i], bv[jj], acc[i][jj]);
    }
    __syncthreads();
  }
#pragma unroll
  for (int i = 0; i < 4; ++i)
#pragma unroll
    for (int jj = 0; jj < 4; ++jj)
      out[(size_t)(n0 + tn + jj) * M + (m0 + tm + i)] = (_Float16)(acc[i][jj] + bias[n0 + tn + jj]);
}

// ---------------- sequential GRU scan, single workgroup, 512 threads ----------------
// Lane pair (2u, 2u+1) owns hidden unit u; each lane of the pair holds ONE
// K-half of the three gate rows (r,z,n) as f16 pairs: 3*64 = 192 VGPRs —
// under the 256 architectural-VGPR cap so promote-alloca keeps them in
// registers. Partial dots accumulate from ZERO and combine via
// __shfl_xor(.,1); bias added ONCE after the reduction (round-2 bug: bias
// was the accumulator seed on both lanes → added twice → 1.9e-2 absmax).
// h broadcast via 1 KB double-buffered LDS. gi is feature-major; one h8v
// load per gate per 8 steps, prefetched a block ahead.

__global__ __launch_bounds__(512, 2) void k_gru_scan(const float* __restrict__ Whh, const float* __restrict__ bhh,
                                                     const _Float16* __restrict__ giT, _Float16* __restrict__ gout,
                                                     int T) {
  int j = threadIdx.x;   // 0..511
  int uu = j >> 1;       // hidden unit 0..255
  int half = j & 1;      // K-half
  h2v wr[64], wz[64], wn[64];
  {
    const float2* r0 = (const float2*)(Whh + (size_t)uu * 256 + half * 128);
    const float2* r1 = (const float2*)(Whh + (size_t)(uu + 256) * 256 + half * 128);
    const float2* r2 = (const float2*)(Whh + (size_t)(uu + 512) * 256 + half * 128);
#pragma unroll
    for (int k = 0; k < 64; ++k) {
      float2 a = r0[k]; h2v va; va.x = (_Float16)a.x; va.y = (_Float16)a.y; wr[k] = va;
      float2 b = r1[k]; h2v vb; vb.x = (_Float16)b.x; vb.y = (_Float16)b.y; wz[k] = vb;
      float2 c = r2[k]; h2v vc; vc.x = (_Float16)c.x; vc.y = (_Float16)c.y; wn[k] = vc;
    }
  }
  float bhr = bhh[uu], bhz = bhh[uu + 256], bhn = bhh[uu + 512];
  __shared__ __align__(16) _Float16 hb[2][256];
  if (j < 256) { hb[0][j] = (_Float16)0.f; hb[1][j] = (_Float16)0.f; }
  __syncthreads();
  float h = 0.f;
  const _Float16* gr_p = giT + (size_t)uu * T;
  const _Float16* gz_p = giT + (size_t)(uu + 256) * T;
  const _Float16* gn_p = giT + (size_t)(uu + 512) * T;
  h8v gr = *(const h8v*)gr_p;
  h8v gz = *(const h8v*)gz_p;
  h8v gn = *(const h8v*)gn_p;
  for (int t0 = 0; t0 < T; t0 += 8) {
    h8v grn = gr, gzn = gz, gnn = gn;
    if (t0 + 8 < T) {
      grn = *(const h8v*)(gr_p + t0 + 8);
      gzn = *(const h8v*)(gz_p + t0 + 8);
      gnn = *(const h8v*)(gn_p + t0 + 8);
    }
    h8v sb;
#pragma unroll
    for (int u = 0; u < 8; ++u) {
      int t = t0 + u;
      float gir = (float)gr[u], giz = (float)gz[u], gin = (float)gn[u];
      const h2v* hp = (const h2v*)(&hb[t & 1][0]) + half * 64;
      float ar = 0.f, az = 0.f, an = 0.f;
#pragma unroll
      for (int k = 0; k < 64; ++k) {
        h2v hk = hp[k];
        ar = fdot2f(wr[k], hk, ar);
        az = fdot2f(wz[k], hk, az);
        an = fdot2f(wn[k], hk, an);
      }
      ar += __shfl_xor(ar, 1);
      az += __shfl_xor(az, 1);
      an += __shfl_xor(an, 1);
      ar += bhr; az += bhz; an += bhn;
      float r = sigf(gir + ar);
      float zt = sigf(giz + az);
      float nn = tanhfast(gin + r * an);
      h = (1.f - zt) * nn + zt * h;
      sb[u] = (_Float16)h;
      if (half == 0) hb[(t & 1) ^ 1][uu] = (_Float16)h;
      __syncthreads();
    }
    if (half == 0) *(h8v*)(gout + (size_t)uu * T + t0) = sb;
    gr = grn; gz = gzn; gn = gnn;
  }
}

// ---------------- final MLP: out[t] = Wlin2 . relu(Wlin1 . g1_t + blin1) + blin2 ----------------

__global__ __launch_bounds__(128) void k_final(const _Float16* __restrict__ g1T, const float* __restrict__ Wlin1,
                                               const float* __restrict__ blin1, const float* __restrict__ Wlin2,
                                               const float* __restrict__ blin2, float* __restrict__ out, int E) {
  int j = threadIdx.x;  // 0..127
  float w[256];
#pragma unroll
  for (int k = 0; k < 256; ++k) w[k] = Wlin1[(size_t)j * 256 + k];
  float bj = blin1[j], w2j = Wlin2[j], b2v = blin2[0];
  __shared__ float gsf[256];
  __shared__ float red[128];
  for (int t = blockIdx.x; t < E; t += gridDim.x) {
    gsf[j] = (float)g1T[(size_t)j * E + t];
    gsf[j + 128] = (float)g1T[(size_t)(j + 128) * E + t];
    __syncthreads();
    float acc = 0.f;
#pragma unroll
    for (int k = 0; k < 256; ++k) acc = fmaf(w[k], gsf[k], acc);
    float v = fmaxf(acc + bj, 0.f) * w2j;
    red[j] = v;
    __syncthreads();
    for (int s = 64; s > 0; s >>= 1) {
      if (j < s) red[j] += red[j + s];
      __syncthreads();
    }
    if (j == 0) out[t] = red[0] + b2v;
    __syncthreads();
  }
}

// ---------------- launch ----------------

extern "C" void kernel_launch(void* const* d_in, const int* in_sizes, int n_in,
                              void* d_out, int out_size, void* d_ws, size_t ws_size,
                              hipStream_t stream) {
  (void)n_in; (void)out_size; (void)ws_size;
  const float* x = (const float*)d_in[0];
  const int* ei = (const int*)d_in[1];
  const float* ea = (const float*)d_in[2];
  const float* W1 = (const float*)d_in[3];
  const float* as1 = (const float*)d_in[4];
  const float* ad1 = (const float*)d_in[5];
  const float* b1 = (const float*)d_in[6];
  const float* gamma1 = (const float*)d_in[7];
  const float* beta1 = (const float*)d_in[8];
  const float* mean1 = (const float*)d_in[9];
  const float* var1 = (const float*)d_in[10];
  const float* W2 = (const float*)d_in[11];
  const float* as2 = (const float*)d_in[12];
  const float* ad2 = (const float*)d_in[13];
  const float* b2 = (const float*)d_in[14];
  const float* gamma2 = (const float*)d_in[15];
  const float* beta2 = (const float*)d_in[16];
  const float* mean2 = (const float*)d_in[17];
  const float* var2 = (const float*)d_in[18];
  const float* Wih0 = (const float*)d_in[19];
  const float* Whh0 = (const float*)d_in[20];
  const float* bih0 = (const float*)d_in[21];
  const float* bhh0 = (const float*)d_in[22];
  const float* Wih1 = (const float*)d_in[23];
  const float* Whh1 = (const float*)d_in[24];
  const float* bih1 = (const float*)d_in[25];
  const float* bhh1 = (const float*)d_in[26];
  const float* Wlin1 = (const float*)d_in[27];
  const float* blin1 = (const float*)d_in[28];
  const float* Wlin2 = (const float*)d_in[29];
  const float* blin2 = (const float*)d_in[30];

  int N = in_sizes[0];
  int E = in_sizes[1] / 2;
  const int* src = ei;
  const int* dst = ei + E;

  char* wsp = (char*)d_ws;
  size_t off = 0;
  auto carve = [&](size_t bytes) -> void* {
    void* p = wsp + off;
    off = (off + bytes + 255) & ~(size_t)255;
    return p;
  };
  float* c12 = (float*)carve(2 * sizeof(float));
  float* a1s = (float*)carve((size_t)N * 4);
  float* a1d = (float*)carve((size_t)N * 4);
  unsigned* m1 = (unsigned*)carve((size_t)N * 4);
  float* z1 = (float*)carve((size_t)N * 4);
  float* uacc = (float*)carve((size_t)N * 4);
  float* h1 = (float*)carve((size_t)N * 256 * 4);
  float* xw2 = (float*)carve((size_t)N * 256 * 4);
  float* a2s = (float*)carve((size_t)N * 4);
  float* a2d = (float*)carve((size_t)N * 4);
  unsigned* m2 = (unsigned*)carve((size_t)N * 4);
  float* z2 = (float*)carve((size_t)N * 4);
  float* acc2 = (float*)carve((size_t)N * 256 * 4);          // becomes h2 in-place
  _Float16* gi = (_Float16*)carve((size_t)E * 768 * 2);      // feature-major [768, E]; reused gi0 then gi1
  _Float16* g0 = (_Float16*)carve((size_t)E * 256 * 2);      // feature-major [256, E]
  _Float16* g1 = (_Float16*)carve((size_t)E * 256 * 2);      // feature-major [256, E]

  hipMemsetAsync(m1, 0, (size_t)N * 4, stream);
  hipMemsetAsync(z1, 0, (size_t)N * 4, stream);
  hipMemsetAsync(uacc, 0, (size_t)N * 4, stream);
  hipMemsetAsync(m2, 0, (size_t)N * 4, stream);
  hipMemsetAsync(z2, 0, (size_t)N * 4, stream);
  hipMemsetAsync(acc2, 0, (size_t)N * 256 * 4, stream);

  int eb = (E + N + 255) / 256;

  k_prep_c<<<1, 256, 0, stream>>>(W1, as1, ad1, c12);
  k_a1<<<(N + 255) / 256, 256, 0, stream>>>(x, c12, a1s, a1d, N);
  k_edge_max<<<eb, 256, 0, stream>>>(a1s, a1d, m1, src, dst, E, N);
  k_gat1_edge_sum<<<eb, 256, 0, stream>>>(a1s, a1d, m1, src, dst, x, z1, uacc, E, N);
  k_gat1_node<<<N, 256, 0, stream>>>(uacc, z1, W1, b1, gamma1, beta1, mean1, var1, h1);

  dim3 gx((N + BM - 1) / BM, 256 / BN);
  k_gemm_f32<<<gx, 256, 0, stream>>>(h1, W2, xw2, N, 256, 256);
  k_rowdots<<<N, 256, 0, stream>>>(xw2, as2, ad2, a2s, a2d);
  k_edge_max<<<eb, 256, 0, stream>>>(a2s, a2d, m2, src, dst, E, N);
  k_gat2_scatter<<<4096, 256, 0, stream>>>(a2s, a2d, m2, src, dst, xw2, z2, acc2, E, N);
  k_gat2_node<<<N, 256, 0, stream>>>(acc2, z2, b2, gamma2, beta2, mean2, var2);

  dim3 gg(E / BM, 768 / BN);
  k_gemm_gi<<<gg, 256, 0, stream>>>(nullptr, acc2, src, dst, ea, Wih0, bih0, gi, E, 768, 515, 0);
  k_gru_scan<<<1, 512, 0, stream>>>(Whh0, bhh0, gi, g0, E);
  k_gemm_gi<<<gg, 256, 0, stream>>>(g0, nullptr, src, dst, ea, Wih1, bih1, gi, E, 768, 256, 1);
  k_gru_scan<<<1, 512, 0, stream>>>(Whh1, bhh1, gi, g1, E);

  k_final<<<1024, 128, 0, stream>>>(g1, Wlin1, blin1, Wlin2, blin2, (float*)d_out, E);
}